// Round 17
// baseline (291.371 us; speedup 1.0000x reference)
//
#include <hip/hip_runtime.h>
#include <hip/hip_bf16.h>

// F2VConv3d: per-face double-GEMM (both on MFMA) then vertex gather + BN.
//   W[f,:] = fc[f,:] @ sw          (MFMA1, K=16 padded to 32, computed as W^T)
//   feat[f,cm] = inp[f,cm>>1] * W[f,cm]   (epilogue: LDS in-place overwrite)
//   g[f] = feat[f,:] @ dw          (MFMA2)
//   out[v] = BN(relu(mean_{f in N(v)} g[f] + bias))
// R17: k_faceg rebuilt as ZERO-BARRIER wave-private pipelines. R16 counters
// showed 13500 cyc/tile vs ~400 of work, all pipes <20%: 5 block barriers x
// 4-wave lockstep at 8 waves/CU was the cost. Now wave w owns faces
// [w*16,w*16+16) end-to-end: private 2x8KB LDS dbuf (own DMA), face-split
// MFMA1 (a1 = all 16 swt tiles, 64 VGPR; single b1), in-place feat,
// MFMA2 with af[8] = whole wave-feat in regs (alias-safe staging), bfr
// streamed from L2-hot dwt per n-tile. Sync = wave-local waitcnt only.

constexpr int C_IN  = 128;
constexpr int KF    = 16;
constexpr int CM    = 256;    // C_IN * MULT
constexpr int C_OUT = 128;
constexpr int CAP   = 32;     // max tracked faces per vertex
constexpr int GB    = 1024;   // k_gather grid (k_red loops over GB)
constexpr int FT    = 64;     // faces per block tile (16 per wave)
constexpr int GRIDF = 512;    // k_faceg grid (2 blocks/CU, 64KB LDS)
constexpr float BN_EPS = 1e-3f;

typedef __attribute__((ext_vector_type(8))) short short8;
typedef __attribute__((ext_vector_type(4))) float f32x4;

__device__ __forceinline__ ushort f2bf(float x) {
  union { float f; unsigned u; } v; v.f = x;
  return (ushort)((v.u + 0x7fffu + ((v.u >> 16) & 1u)) >> 16);
}
__device__ __forceinline__ float b2f(ushort u) {
  return __uint_as_float((unsigned)u << 16);
}
__device__ __forceinline__ uint pk2(float a, float b) {
  __hip_bfloat162 h = __float22bfloat162_rn(float2{a, b});
  return *(uint*)&h;
}
__device__ __forceinline__ void dma16(const float* g, void* l) {
  __builtin_amdgcn_global_load_lds(
      (const __attribute__((address_space(1))) void*)g,
      (__attribute__((address_space(3))) void*)l, 16, 0, 0);
}
// wave-local fences (rule #18: sched_barrier after inline-asm waitcnt)
__device__ __forceinline__ void fence_lds() {
  asm volatile("s_waitcnt lgkmcnt(0)" ::: "memory");
  __builtin_amdgcn_sched_barrier(0);
}
__device__ __forceinline__ void fence_vm() {
  asm volatile("s_waitcnt vmcnt(0)" ::: "memory");
  __builtin_amdgcn_sched_barrier(0);
}

// Merged prep + fill. Blocks 0..95: dwt/swt transform. Blocks 96..: CSR fill.
__global__ __launch_bounds__(256) void k_prepfill(
    const float* __restrict__ dw, const float* __restrict__ sw,
    ushort* __restrict__ dwt, ushort* __restrict__ swt,
    const int* __restrict__ face, const int* __restrict__ vt_map,
    int* __restrict__ cnt, int* __restrict__ slots, int n_inc) {
  const int b = blockIdx.x, tid = threadIdx.x;
  if (b < 64) {                       // dwt: 128*256 elems, 2/thread
    int i = b * 512 + tid;
#pragma unroll
    for (int r = 0; r < 2; ++r, i += 256) {
      int n = i >> 8, k = i & 255;
      dwt[i] = f2bf(dw[k * C_OUT + n]);
    }
  } else if (b < 96) {                // swt: 256*32 elems, 1/thread
    int i = (b - 64) * 256 + tid;
    int cm = i >> 5, k = i & 31;
    swt[i] = (k < KF) ? f2bf(sw[k * CM + cm]) : (ushort)0;
  } else {                            // fill
    int i = (b - 96) * 256 + tid;
    if (i < n_inc) {
      int f = i / 3;
      int v = vt_map[face[i]];
      int p = atomicAdd(&cnt[v], 1);
      if (p < CAP) slots[(size_t)v * CAP + p] = f;
    }
  }
}

// Zero-barrier wave-private k_faceg. Per wave per tile:
// [vmcnt(0): own DMA landed] [fc loads; DMA next buf] [b1] [16x MFMA1 +
// in-place epi] [lgkm fence] [af[8] = whole feat -> regs] [lgkm fence]
// [8x (bfr load + 8 MFMA2 + f32 staging over feat)] [lgkm fence]
// [pack bf16 + global g store].
__global__ __launch_bounds__(256, 2) void k_faceg(
    const float* __restrict__ inp, const float* __restrict__ fc,
    const ushort* __restrict__ swt, const ushort* __restrict__ dwt,
    ushort* __restrict__ g, int ntiles) {
  __shared__ __align__(1024) char s_lds[4][2][8192];   // per-wave dbuf, 64KB

  const int tid  = threadIdx.x;
  const int w    = tid >> 6;
  const int lane = tid & 63;
  const int rm   = lane & 15;
  const int kg   = lane >> 4;

  char* wbase = &s_lds[w][0][0];

  // MFMA1 A-frags: ALL 16 swt cm-tiles (64 VGPR), loop-invariant
  short8 a1[16];
#pragma unroll
  for (int ct = 0; ct < 16; ++ct)
    a1[ct] = *(const short8*)&swt[(size_t)(ct * 16 + rm) * 32 + kg * 8];

  // DMA wave's 16 inp rows (8KB) into buf, source-swizzled (chunk ^= row&7)
  auto issue_dma = [&](int buf, int fb) {
#pragma unroll
    for (int it = 0; it < 8; ++it) {
      const int row   = it * 2 + (lane >> 5);          // local face 0..15
      const int chunk = lane & 31;
      const float* src = inp + (size_t)(fb + w * 16 + row) * C_IN
                       + ((chunk ^ (row & 7)) << 2);
      dma16(src, wbase + buf * 8192 + it * 1024);
    }
  };

  int t = blockIdx.x;
  issue_dma(0, t * FT);
  int cur = 0;

  for (; t < ntiles; t += GRIDF, cur ^= 1) {
    const int fb = t * FT;
    char* sb = wbase + cur * 8192;

    fence_vm();                       // own DMA for this tile landed

    // fc for wave's 16 faces (B-operand of MFMA1)
    const float* fr = &fc[(size_t)(fb + w * 16 + rm) * KF + (kg & 1) * 8];
    const float4 p0 = *(const float4*)fr;
    const float4 p1 = *(const float4*)(fr + 4);

    const int tn = t + GRIDF;
    if (tn < ntiles) issue_dma(cur ^ 1, tn * FT);   // full tile to land

    short8 b1;
    {
      uint4 u;
      u.x = pk2(p0.x, p0.y); u.y = pk2(p0.z, p0.w);
      u.z = pk2(p1.x, p1.y); u.w = pk2(p1.z, p1.w);
      if (kg >= 2) u = uint4{0, 0, 0, 0};           // K padded 16->32
      b1 = *(short8*)&u;
    }

    // MFMA1 + in-place epilogue (wave-private rows; feat bf16 over inp f32)
    // D layout (m89): col=rm=face_local, row=kg*4+r=cm_local
#pragma unroll
    for (int ct = 0; ct < 16; ++ct) {
      f32x4 acc = {0.f, 0.f, 0.f, 0.f};
      acc = __builtin_amdgcn_mfma_f32_16x16x32_bf16(a1[ct], b1, acc, 0, 0, 0);
      const int face = rm;
      const int cmb  = ct * 16 + kg * 4;
      const int byt  = face * 512 + ((((cmb * 2) >> 4) ^ (face & 7)) << 4)
                     + ((cmb * 2) & 15);
      const float2 ivv = *(const float2*)(sb + byt);
      uint2 pw;
      pw.x = pk2(acc[0] * ivv.x, acc[1] * ivv.x);
      pw.y = pk2(acc[2] * ivv.y, acc[3] * ivv.y);
      *(uint2*)(sb + byt) = pw;
    }

    fence_lds();                      // feat writes done (own wave)

    // whole wave-feat -> registers (8KB, read once; enables alias-safe staging)
    short8 af[8];
#pragma unroll
    for (int ks = 0; ks < 8; ++ks) {
      const int byt = rm * 512 + (((ks * 4 + kg) ^ (rm & 7)) << 4);
      af[ks] = *(const short8*)(sb + byt);
    }
    fence_lds();                      // af in regs; feat region now reusable

    // MFMA2 per n-tile: bfr streamed from L2-hot dwt; staging over feat
#pragma unroll
    for (int nt = 0; nt < 8; ++nt) {
      short8 bfr[8];
#pragma unroll
      for (int ks = 0; ks < 8; ++ks)
        bfr[ks] = *(const short8*)&dwt[(nt * 16 + rm) * 256 + ks * 32 + kg * 8];
      f32x4 acc = {0.f, 0.f, 0.f, 0.f};
#pragma unroll
      for (int ks = 0; ks < 8; ++ks)
        acc = __builtin_amdgcn_mfma_f32_16x16x32_bf16(af[ks], bfr[ks], acc, 0, 0, 0);
      // D: col=rm -> ch nt*16+rm; row=kg*4+r -> face
#pragma unroll
      for (int r = 0; r < 4; ++r) {
        const int face = kg * 4 + r;
        const int col  = nt * 16 + rm;
        const int byt  = face * 512 + (((col >> 2) ^ (face & 7)) << 4)
                       + (col & 3) * 4;
        *(float*)(sb + byt) = acc[r];
      }
    }

    fence_lds();                      // staging ready (own wave)

    // pack bf16 + store: wave's 16 rows, chunk pairs 2q+8i (bank-spread)
    const int row = lane >> 2;        // local face 0..15
    const int q   = lane & 3;
#pragma unroll
    for (int i = 0; i < 4; ++i) {
      const int c0 = 2 * q + 8 * i;
      const float4 a = *(const float4*)(sb + row * 512 + ((c0 ^ (row & 7)) << 4));
      const float4 b = *(const float4*)(sb + row * 512 + (((c0 + 1) ^ (row & 7)) << 4));
      uint4 u;
      u.x = pk2(a.x, a.y); u.y = pk2(a.z, a.w);
      u.z = pk2(b.x, b.y); u.w = pk2(b.z, b.w);
      *(short8*)&g[(size_t)(fb + w * 16 + row) * C_OUT + c0 * 4] = *(short8*)&u;
    }
  }
}

// 16 verts/tile, 16 threads/vert. Writes bf16 pre-BN buffer (half traffic);
// partials transposed part[col][GB]. No per-tile LDS/barriers.
__global__ __launch_bounds__(256) void k_gather(
    const ushort* __restrict__ g, const int* __restrict__ cnt,
    const int* __restrict__ slots, const int* __restrict__ nf_cnt,
    const float* __restrict__ bias, ushort* __restrict__ pre,
    float* __restrict__ part, int nv, int ntiles) {
  __shared__ float s_red[256][8];

  const int tid = threadIdx.x;
  const int q   = tid & 15;
  const int vg  = tid >> 4;
  const int c8  = q * 8;

  float bs[8];
#pragma unroll
  for (int j = 0; j < 8; ++j) bs[j] = bias[c8 + j];
  float st_s[8], st_q[8];
#pragma unroll
  for (int j = 0; j < 8; ++j) { st_s[j] = 0.f; st_q[j] = 0.f; }

  for (int tile = blockIdx.x; tile < ntiles; tile += gridDim.x) {
    const int v = tile * 16 + vg;
    int deg = cnt[v]; deg = deg > CAP ? CAP : deg;      // lane-broadcast
    const int* sl = &slots[(size_t)v * CAP];

    float a[8];
#pragma unroll
    for (int j = 0; j < 8; ++j) a[j] = 0.f;

    int t = 0;
    for (; t + 4 <= deg; t += 4) {
      const int4 ff = *(const int4*)&sl[t];             // broadcast 16B
      const short8 r0 = *(const short8*)&g[(size_t)ff.x * C_OUT + c8];
      const short8 r1 = *(const short8*)&g[(size_t)ff.y * C_OUT + c8];
      const short8 r2 = *(const short8*)&g[(size_t)ff.z * C_OUT + c8];
      const short8 r3 = *(const short8*)&g[(size_t)ff.w * C_OUT + c8];
#pragma unroll
      for (int j = 0; j < 8; ++j)
        a[j] += (b2f((ushort)r0[j]) + b2f((ushort)r1[j]))
              + (b2f((ushort)r2[j]) + b2f((ushort)r3[j]));
    }
    for (; t < deg; ++t) {
      const short8 r0 = *(const short8*)&g[(size_t)sl[t] * C_OUT + c8];
#pragma unroll
      for (int j = 0; j < 8; ++j) a[j] += b2f((ushort)r0[j]);
    }

    int d = nf_cnt[v]; if (d < 1) d = 1;
    const float inv = 1.0f / (float)d;
    float r[8];
#pragma unroll
    for (int j = 0; j < 8; ++j) {
      r[j] = fmaxf(fmaf(a[j], inv, bs[j]), 0.f);
      st_s[j] += r[j];
      st_q[j] = fmaf(r[j], r[j], st_q[j]);
    }
    uint4 u;
    u.x = pk2(r[0], r[1]); u.y = pk2(r[2], r[3]);
    u.z = pk2(r[4], r[5]); u.w = pk2(r[6], r[7]);
    *(short8*)&pre[(size_t)v * C_OUT + c8] = *(short8*)&u;
  }

  // deterministic block partials: part[col][GB] (transposed)
#pragma unroll
  for (int j = 0; j < 8; ++j) s_red[tid][j] = st_s[j];
  __syncthreads();
  if (tid < 16) {
    for (int j = 0; j < 8; ++j) {
      float x = 0.f;
      for (int gg = 0; gg < 16; ++gg) x += s_red[gg * 16 + tid][j];
      part[(size_t)(tid * 8 + j) * GB + blockIdx.x] = x;
    }
  }
  __syncthreads();
#pragma unroll
  for (int j = 0; j < 8; ++j) s_red[tid][j] = st_q[j];
  __syncthreads();
  if (tid < 16) {
    for (int j = 0; j < 8; ++j) {
      float x = 0.f;
      for (int gg = 0; gg < 16; ++gg) x += s_red[gg * 16 + tid][j];
      part[(size_t)(128 + tid * 8 + j) * GB + blockIdx.x] = x;
    }
  }
}

// 256 blocks: block j reduces part[j][0:GB] (coalesced) -> red[j].
__global__ __launch_bounds__(256) void k_red(const float* __restrict__ part,
                                             float* __restrict__ red) {
  const int j   = blockIdx.x;
  const int tid = threadIdx.x;
  float v = 0.f;
#pragma unroll
  for (int b = 0; b < GB; b += 256) v += part[(size_t)j * GB + b + tid];
#pragma unroll
  for (int off = 32; off > 0; off >>= 1) v += __shfl_down(v, off);
  __shared__ float sred[4];
  if ((tid & 63) == 0) sred[tid >> 6] = v;
  __syncthreads();
  if (tid == 0) red[j] = sred[0] + sred[1] + sred[2] + sred[3];
}

__global__ void k_fin(const float* __restrict__ red,
                      const float* __restrict__ gamma, const float* __restrict__ beta,
                      float* __restrict__ scale, float* __restrict__ shift, float invN) {
  int o = threadIdx.x;   // 128
  float mean = red[o] * invN;
  float var  = red[128 + o] * invN - mean * mean;
  float sc   = gamma[o] * rsqrtf(var + BN_EPS);
  scale[o] = sc;
  shift[o] = fmaf(-mean, sc, beta[o]);
}

// Read bf16 pre (25.6MB), apply affine, write f32 out (51.2MB).
__global__ __launch_bounds__(256) void k_bn(const ushort* __restrict__ pre,
                                            const float* __restrict__ scale,
                                            const float* __restrict__ shift,
                                            float* __restrict__ out, int n8) {
  int idx = blockIdx.x * blockDim.x + threadIdx.x;
  const int stride = gridDim.x * blockDim.x;
  for (; idx < n8; idx += stride) {
    const short8 pv = *(const short8*)&pre[(size_t)idx * 8];
    const int base = (idx * 8) & (C_OUT - 1);
    const float4 sc0 = *(const float4*)&scale[base];
    const float4 sc1 = *(const float4*)&scale[base + 4];
    const float4 sh0 = *(const float4*)&shift[base];
    const float4 sh1 = *(const float4*)&shift[base + 4];
    float4 o0, o1;
    o0.x = fmaf(b2f((ushort)pv[0]), sc0.x, sh0.x);
    o0.y = fmaf(b2f((ushort)pv[1]), sc0.y, sh0.y);
    o0.z = fmaf(b2f((ushort)pv[2]), sc0.z, sh0.z);
    o0.w = fmaf(b2f((ushort)pv[3]), sc0.w, sh0.w);
    o1.x = fmaf(b2f((ushort)pv[4]), sc1.x, sh1.x);
    o1.y = fmaf(b2f((ushort)pv[5]), sc1.y, sh1.y);
    o1.z = fmaf(b2f((ushort)pv[6]), sc1.z, sh1.z);
    o1.w = fmaf(b2f((ushort)pv[7]), sc1.w, sh1.w);
    *(float4*)&out[(size_t)idx * 8]     = o0;
    *(float4*)&out[(size_t)idx * 8 + 4] = o1;
  }
}

extern "C" void kernel_launch(void* const* d_in, const int* in_sizes, int n_in,
                              void* d_out, int out_size, void* d_ws, size_t ws_size,
                              hipStream_t stream) {
  const float* inputs = (const float*)d_in[0];
  const float* fc     = (const float*)d_in[1];
  const int*   face   = (const int*)d_in[2];
  const int*   nf_cnt = (const int*)d_in[3];
  const int*   vt_map = (const int*)d_in[4];
  const float* sw     = (const float*)d_in[5];
  const float* dw     = (const float*)d_in[6];
  const float* bias   = (const float*)d_in[7];
  const float* gamma  = (const float*)d_in[8];
  const float* beta   = (const float*)d_in[9];
  float* out = (float*)d_out;

  const int nf = in_sizes[0] / C_IN;   // 200000
  const int nv = in_sizes[3];          // 100000

  // ws: cnt[nv] | scale[128] | shift[128] | red[256] | part[256*GB]
  //     | dwt[128*256 u16] | swt[256*32 u16] | slots[nv*CAP]
  //     | g[nf*128 u16] | pre[nv*128 u16]
  char* p = (char*)d_ws;
  int*    cnt   = (int*)p;            p += (size_t)nv * 4;
  float*  scale = (float*)p;          p += C_OUT * 4;
  float*  shift = (float*)p;          p += C_OUT * 4;
  float*  red   = (float*)p;          p += 256 * 4;
  float*  part  = (float*)p;          p += (size_t)256 * GB * 4;
  ushort* dwt   = (ushort*)p;         p += (size_t)C_OUT * CM * 2;
  ushort* swt   = (ushort*)p;         p += (size_t)CM * 32 * 2;
  int*    slots = (int*)p;            p += (size_t)nv * CAP * 4;
  ushort* g     = (ushort*)p;         p += (size_t)nf * C_OUT * 2;
  ushort* pre   = (ushort*)p;

  hipMemsetAsync(cnt, 0, (size_t)nv * 4, stream);

  const int n_inc = nf * 3;
  const int fill_blocks = (n_inc + 255) / 256;
  k_prepfill<<<96 + fill_blocks, 256, 0, stream>>>(dw, sw, dwt, swt,
                                                   face, vt_map, cnt, slots, n_inc);

  const int ntiles_f = (nf + FT - 1) / FT;   // 3125
  k_faceg<<<GRIDF, 256, 0, stream>>>(inputs, fc, swt, dwt, g, ntiles_f);

  const int ntiles_v = (nv + 15) / 16;       // 6250
  k_gather<<<GB, 256, 0, stream>>>(g, cnt, slots, nf_cnt, bias, pre, part, nv, ntiles_v);

  k_red<<<256, 256, 0, stream>>>(part, red);
  k_fin<<<1, 128, 0, stream>>>(red, gamma, beta, scale, shift, 1.0f / (float)nv);

  const int n8 = (nv * C_OUT) / 8;           // 1.6M
  k_bn<<<2048, 256, 0, stream>>>(pre, scale, shift, out, n8);
}

// Round 18
// 137.116 us; speedup vs baseline: 2.1250x; 2.1250x over previous
//
#include <hip/hip_runtime.h>
#include <hip/hip_bf16.h>

// F2VConv3d: per-face double-GEMM (both on MFMA) then vertex gather + BN.
//   W[f,:] = fc[f,:] @ sw          (MFMA1, K=16 padded to 32, computed as W^T)
//   feat[f,cm] = inp[f,cm>>1] * W[f,cm]   (epilogue: LDS in-place overwrite)
//   g[f] = feat[f,:] @ dw          (MFMA2, SWAPPED operands -> D = g^T frags)
//   out[v] = BN(relu(mean_{f in N(v)} g[f] + bias))
// R18: base = R16 (best, 135.5us; faceg 69us clean). One change: MFMA2 uses
// mfma(bfr, af, .) — A/B fragments share the same lane layout, so swapping
// roles gives D[row=channel][col=face]: each lane holds 4 consecutive
// channels of ONE face row -> cvt_pk + direct 8B global store (4 kg-groups
// form a 32B contiguous row segment). Deletes the f32 LDS staging phase
// (source of the 3.3M bank-conflict cycles) and barriers C+D (5 -> 3).
// R17 lesson re-confirmed: loop-invariant frag set must stay ~<110 VGPR.

constexpr int C_IN  = 128;
constexpr int KF    = 16;
constexpr int CM    = 256;    // C_IN * MULT
constexpr int C_OUT = 128;
constexpr int CAP   = 32;     // max tracked faces per vertex
constexpr int GB    = 1024;   // k_gather grid (k_red loops over GB)
constexpr int FT    = 64;     // faces per k_faceg tile
constexpr int GRIDF = 512;    // k_faceg grid (2 blocks/CU with 64KB LDS)
constexpr float BN_EPS = 1e-3f;

typedef __attribute__((ext_vector_type(8))) short short8;
typedef __attribute__((ext_vector_type(4))) float f32x4;

__device__ __forceinline__ ushort f2bf(float x) {
  union { float f; unsigned u; } v; v.f = x;
  return (ushort)((v.u + 0x7fffu + ((v.u >> 16) & 1u)) >> 16);
}
__device__ __forceinline__ float b2f(ushort u) {
  return __uint_as_float((unsigned)u << 16);
}
__device__ __forceinline__ uint pk2(float a, float b) {
  __hip_bfloat162 h = __float22bfloat162_rn(float2{a, b});
  return *(uint*)&h;
}
__device__ __forceinline__ void dma16(const float* g, void* l) {
  __builtin_amdgcn_global_load_lds(
      (const __attribute__((address_space(1))) void*)g,
      (__attribute__((address_space(3))) void*)l, 16, 0, 0);
}
__device__ __forceinline__ void bar_raw() {
  __builtin_amdgcn_s_barrier();
  asm volatile("" ::: "memory");
}
__device__ __forceinline__ void bar_lds() {
  asm volatile("s_waitcnt lgkmcnt(0)" ::: "memory");
  __builtin_amdgcn_s_barrier();
  asm volatile("" ::: "memory");
}

// Merged prep + fill. Blocks 0..95: dwt/swt transform. Blocks 96..: CSR fill.
__global__ __launch_bounds__(256) void k_prepfill(
    const float* __restrict__ dw, const float* __restrict__ sw,
    ushort* __restrict__ dwt, ushort* __restrict__ swt,
    const int* __restrict__ face, const int* __restrict__ vt_map,
    int* __restrict__ cnt, int* __restrict__ slots, int n_inc) {
  const int b = blockIdx.x, tid = threadIdx.x;
  if (b < 64) {                       // dwt: 128*256 elems, 2/thread
    int i = b * 512 + tid;
#pragma unroll
    for (int r = 0; r < 2; ++r, i += 256) {
      int n = i >> 8, k = i & 255;
      dwt[i] = f2bf(dw[k * C_OUT + n]);
    }
  } else if (b < 96) {                // swt: 256*32 elems, 1/thread
    int i = (b - 64) * 256 + tid;
    int cm = i >> 5, k = i & 31;
    swt[i] = (k < KF) ? f2bf(sw[k * CM + cm]) : (ushort)0;
  } else {                            // fill
    int i = (b - 96) * 256 + tid;
    if (i < n_inc) {
      int f = i / 3;
      int v = vt_map[face[i]];
      int p = atomicAdd(&cnt[v], 1);
      if (p < CAP) slots[(size_t)v * CAP + p] = f;
    }
  }
}

// Persistent pipelined k_faceg: FT=64, 2x32KB dbuf, 2 blocks/CU, counted
// vmcnt(8), raw barriers. Per tile: [TOP bar_lds] [fc loads, prefetch-DMA
// next] [vmcnt(8)] [b1 build] [bar A] [MFMA1+epi in-place] [bar B]
// [MFMA2 swapped + pack + direct g stores].  (3 barriers/tile)
__global__ __launch_bounds__(256, 2) void k_faceg(
    const float* __restrict__ inp, const float* __restrict__ fc,
    const ushort* __restrict__ swt, const ushort* __restrict__ dwt,
    ushort* __restrict__ g, int ntiles) {
  __shared__ __align__(1024) ushort s_buf[2][FT * 256];   // 2 x 32768 B

  const int tid  = threadIdx.x;
  const int w    = tid >> 6;        // wave -> cm range [w*64, w*64+64)
  const int lane = tid & 63;
  const int rm   = lane & 15;
  const int kg   = lane >> 4;

  // loop-invariant fragments (budget: launch_bounds(256,2) -> 256 VGPR)
  short8 a1[4];
#pragma unroll
  for (int ct = 0; ct < 4; ++ct)
    a1[ct] = *(const short8*)&swt[(size_t)(w * 64 + ct * 16 + rm) * 32 + kg * 8];
  short8 bfr[2][8];
#pragma unroll
  for (int nt = 0; nt < 2; ++nt) {
    const int n = (w * 2 + nt) * 16 + rm;
#pragma unroll
    for (int ks = 0; ks < 8; ++ks)
      bfr[nt][ks] = *(const short8*)&dwt[n * 256 + ks * 32 + kg * 8];
  }

  auto issue_dma = [&](int buf, int fb) {
#pragma unroll
    for (int it = 0; it < 8; ++it) {
      const int row   = w * 16 + it * 2 + (lane >> 5);
      const int chunk = lane & 31;
      const float* src = inp + (size_t)(fb + row) * C_IN + ((chunk ^ (row & 7)) << 2);
      dma16(src, (char*)s_buf + buf * 32768 + w * 8192 + it * 1024);
    }
  };

  int t = blockIdx.x;
  issue_dma(0, t * FT);
  int cur = 0;

  for (; t < ntiles; t += GRIDF, cur ^= 1) {
    const int fb = t * FT;
    char* sb = (char*)s_buf + cur * 32768;

    bar_lds();                        // TOP: prev iter's LDS reads drained

    float4 p0[4], p1[4];
#pragma unroll
    for (int ft = 0; ft < 4; ++ft) {
      const float* fr = &fc[(size_t)(fb + ft * 16 + rm) * KF + (kg & 1) * 8];
      p0[ft] = *(const float4*)fr;
      p1[ft] = *(const float4*)(fr + 4);
    }

    const int tn = t + GRIDF;
    if (tn < ntiles) {
      issue_dma(cur ^ 1, tn * FT);
      asm volatile("s_waitcnt vmcnt(8)" ::: "memory");
    } else {
      asm volatile("s_waitcnt vmcnt(0)" ::: "memory");
    }

    short8 b1[4];
#pragma unroll
    for (int ft = 0; ft < 4; ++ft) {
      uint4 u;
      u.x = pk2(p0[ft].x, p0[ft].y); u.y = pk2(p0[ft].z, p0[ft].w);
      u.z = pk2(p1[ft].x, p1[ft].y); u.w = pk2(p1[ft].z, p1[ft].w);
      if (kg >= 2) u = uint4{0, 0, 0, 0};
      b1[ft] = *(short8*)&u;
    }

    bar_raw();                        // A: buf[cur] fully DMA'd

    // MFMA1 + epilogue: feat bf16 overwrites inp f32 in place
#pragma unroll
    for (int ft = 0; ft < 4; ++ft) {
#pragma unroll
      for (int ct = 0; ct < 4; ++ct) {
        f32x4 acc = {0.f, 0.f, 0.f, 0.f};
        acc = __builtin_amdgcn_mfma_f32_16x16x32_bf16(a1[ct], b1[ft], acc, 0, 0, 0);
        const int face = ft * 16 + rm;
        const int cmb  = w * 64 + ct * 16 + kg * 4;
        const int byt  = face * 512 + ((((cmb * 2) >> 4) ^ (face & 7)) << 4)
                       + ((cmb * 2) & 15);
        const float2 ivv = *(const float2*)(sb + byt);
        uint2 pw;
        pw.x = pk2(acc[0] * ivv.x, acc[1] * ivv.x);
        pw.y = pk2(acc[2] * ivv.y, acc[3] * ivv.y);
        *(uint2*)(sb + byt) = pw;
      }
    }

    bar_lds();                        // B: feat ready

    // MFMA2 with SWAPPED operands: A=bfr (dw^T), B=af (feat) ->
    // D[row=channel][col=face]: lane rm = face, channels (w*2+nt)*16+kg*4+r.
    f32x4 acc2[4][2];
#pragma unroll
    for (int fs = 0; fs < 4; ++fs)
#pragma unroll
      for (int nt = 0; nt < 2; ++nt)
        acc2[fs][nt] = (f32x4){0.f, 0.f, 0.f, 0.f};

#pragma unroll
    for (int fs = 0; fs < 4; ++fs)
#pragma unroll
      for (int ks = 0; ks < 8; ++ks) {
        const int row = fs * 16 + rm;
        const int byt = row * 512 + (((ks * 4 + kg) ^ (row & 7)) << 4);
        const short8 af = *(const short8*)(sb + byt);
        acc2[fs][0] = __builtin_amdgcn_mfma_f32_16x16x32_bf16(bfr[0][ks], af, acc2[fs][0], 0, 0, 0);
        acc2[fs][1] = __builtin_amdgcn_mfma_f32_16x16x32_bf16(bfr[1][ks], af, acc2[fs][1], 0, 0, 0);
      }

    // pack + direct g stores: lane -> face fs*16+rm, 4 channels per nt (8B);
    // the 4 kg-groups of one rm form a contiguous 32B row segment.
#pragma unroll
    for (int fs = 0; fs < 4; ++fs) {
      const size_t rowoff = (size_t)(fb + fs * 16 + rm) * C_OUT;
#pragma unroll
      for (int nt = 0; nt < 2; ++nt) {
        uint2 pw;
        pw.x = pk2(acc2[fs][nt][0], acc2[fs][nt][1]);
        pw.y = pk2(acc2[fs][nt][2], acc2[fs][nt][3]);
        *(uint2*)&g[rowoff + (w * 2 + nt) * 16 + kg * 4] = pw;
      }
    }
  }
}

// 16 verts/tile, 16 threads/vert. Writes bf16 pre-BN buffer (half traffic);
// partials transposed part[col][GB]. No per-tile LDS/barriers.
__global__ __launch_bounds__(256) void k_gather(
    const ushort* __restrict__ g, const int* __restrict__ cnt,
    const int* __restrict__ slots, const int* __restrict__ nf_cnt,
    const float* __restrict__ bias, ushort* __restrict__ pre,
    float* __restrict__ part, int nv, int ntiles) {
  __shared__ float s_red[256][8];

  const int tid = threadIdx.x;
  const int q   = tid & 15;
  const int vg  = tid >> 4;
  const int c8  = q * 8;

  float bs[8];
#pragma unroll
  for (int j = 0; j < 8; ++j) bs[j] = bias[c8 + j];
  float st_s[8], st_q[8];
#pragma unroll
  for (int j = 0; j < 8; ++j) { st_s[j] = 0.f; st_q[j] = 0.f; }

  for (int tile = blockIdx.x; tile < ntiles; tile += gridDim.x) {
    const int v = tile * 16 + vg;
    int deg = cnt[v]; deg = deg > CAP ? CAP : deg;      // lane-broadcast
    const int* sl = &slots[(size_t)v * CAP];

    float a[8];
#pragma unroll
    for (int j = 0; j < 8; ++j) a[j] = 0.f;

    int t = 0;
    for (; t + 4 <= deg; t += 4) {
      const int4 ff = *(const int4*)&sl[t];             // broadcast 16B
      const short8 r0 = *(const short8*)&g[(size_t)ff.x * C_OUT + c8];
      const short8 r1 = *(const short8*)&g[(size_t)ff.y * C_OUT + c8];
      const short8 r2 = *(const short8*)&g[(size_t)ff.z * C_OUT + c8];
      const short8 r3 = *(const short8*)&g[(size_t)ff.w * C_OUT + c8];
#pragma unroll
      for (int j = 0; j < 8; ++j)
        a[j] += (b2f((ushort)r0[j]) + b2f((ushort)r1[j]))
              + (b2f((ushort)r2[j]) + b2f((ushort)r3[j]));
    }
    for (; t < deg; ++t) {
      const short8 r0 = *(const short8*)&g[(size_t)sl[t] * C_OUT + c8];
#pragma unroll
      for (int j = 0; j < 8; ++j) a[j] += b2f((ushort)r0[j]);
    }

    int d = nf_cnt[v]; if (d < 1) d = 1;
    const float inv = 1.0f / (float)d;
    float r[8];
#pragma unroll
    for (int j = 0; j < 8; ++j) {
      r[j] = fmaxf(fmaf(a[j], inv, bs[j]), 0.f);
      st_s[j] += r[j];
      st_q[j] = fmaf(r[j], r[j], st_q[j]);
    }
    uint4 u;
    u.x = pk2(r[0], r[1]); u.y = pk2(r[2], r[3]);
    u.z = pk2(r[4], r[5]); u.w = pk2(r[6], r[7]);
    *(short8*)&pre[(size_t)v * C_OUT + c8] = *(short8*)&u;
  }

  // deterministic block partials: part[col][GB] (transposed)
#pragma unroll
  for (int j = 0; j < 8; ++j) s_red[tid][j] = st_s[j];
  __syncthreads();
  if (tid < 16) {
    for (int j = 0; j < 8; ++j) {
      float x = 0.f;
      for (int gg = 0; gg < 16; ++gg) x += s_red[gg * 16 + tid][j];
      part[(size_t)(tid * 8 + j) * GB + blockIdx.x] = x;
    }
  }
  __syncthreads();
#pragma unroll
  for (int j = 0; j < 8; ++j) s_red[tid][j] = st_q[j];
  __syncthreads();
  if (tid < 16) {
    for (int j = 0; j < 8; ++j) {
      float x = 0.f;
      for (int gg = 0; gg < 16; ++gg) x += s_red[gg * 16 + tid][j];
      part[(size_t)(128 + tid * 8 + j) * GB + blockIdx.x] = x;
    }
  }
}

// 256 blocks: block j reduces part[j][0:GB] (coalesced) -> red[j].
__global__ __launch_bounds__(256) void k_red(const float* __restrict__ part,
                                             float* __restrict__ red) {
  const int j   = blockIdx.x;
  const int tid = threadIdx.x;
  float v = 0.f;
#pragma unroll
  for (int b = 0; b < GB; b += 256) v += part[(size_t)j * GB + b + tid];
#pragma unroll
  for (int off = 32; off > 0; off >>= 1) v += __shfl_down(v, off);
  __shared__ float sred[4];
  if ((tid & 63) == 0) sred[tid >> 6] = v;
  __syncthreads();
  if (tid == 0) red[j] = sred[0] + sred[1] + sred[2] + sred[3];
}

__global__ void k_fin(const float* __restrict__ red,
                      const float* __restrict__ gamma, const float* __restrict__ beta,
                      float* __restrict__ scale, float* __restrict__ shift, float invN) {
  int o = threadIdx.x;   // 128
  float mean = red[o] * invN;
  float var  = red[128 + o] * invN - mean * mean;
  float sc   = gamma[o] * rsqrtf(var + BN_EPS);
  scale[o] = sc;
  shift[o] = fmaf(-mean, sc, beta[o]);
}

// Read bf16 pre (25.6MB), apply affine, write f32 out (51.2MB).
__global__ __launch_bounds__(256) void k_bn(const ushort* __restrict__ pre,
                                            const float* __restrict__ scale,
                                            const float* __restrict__ shift,
                                            float* __restrict__ out, int n8) {
  int idx = blockIdx.x * blockDim.x + threadIdx.x;
  const int stride = gridDim.x * blockDim.x;
  for (; idx < n8; idx += stride) {
    const short8 pv = *(const short8*)&pre[(size_t)idx * 8];
    const int base = (idx * 8) & (C_OUT - 1);
    const float4 sc0 = *(const float4*)&scale[base];
    const float4 sc1 = *(const float4*)&scale[base + 4];
    const float4 sh0 = *(const float4*)&shift[base];
    const float4 sh1 = *(const float4*)&shift[base + 4];
    float4 o0, o1;
    o0.x = fmaf(b2f((ushort)pv[0]), sc0.x, sh0.x);
    o0.y = fmaf(b2f((ushort)pv[1]), sc0.y, sh0.y);
    o0.z = fmaf(b2f((ushort)pv[2]), sc0.z, sh0.z);
    o0.w = fmaf(b2f((ushort)pv[3]), sc0.w, sh0.w);
    o1.x = fmaf(b2f((ushort)pv[4]), sc1.x, sh1.x);
    o1.y = fmaf(b2f((ushort)pv[5]), sc1.y, sh1.y);
    o1.z = fmaf(b2f((ushort)pv[6]), sc1.z, sh1.z);
    o1.w = fmaf(b2f((ushort)pv[7]), sc1.w, sh1.w);
    *(float4*)&out[(size_t)idx * 8]     = o0;
    *(float4*)&out[(size_t)idx * 8 + 4] = o1;
  }
}

extern "C" void kernel_launch(void* const* d_in, const int* in_sizes, int n_in,
                              void* d_out, int out_size, void* d_ws, size_t ws_size,
                              hipStream_t stream) {
  const float* inputs = (const float*)d_in[0];
  const float* fc     = (const float*)d_in[1];
  const int*   face   = (const int*)d_in[2];
  const int*   nf_cnt = (const int*)d_in[3];
  const int*   vt_map = (const int*)d_in[4];
  const float* sw     = (const float*)d_in[5];
  const float* dw     = (const float*)d_in[6];
  const float* bias   = (const float*)d_in[7];
  const float* gamma  = (const float*)d_in[8];
  const float* beta   = (const float*)d_in[9];
  float* out = (float*)d_out;

  const int nf = in_sizes[0] / C_IN;   // 200000
  const int nv = in_sizes[3];          // 100000

  // ws: cnt[nv] | scale[128] | shift[128] | red[256] | part[256*GB]
  //     | dwt[128*256 u16] | swt[256*32 u16] | slots[nv*CAP]
  //     | g[nf*128 u16] | pre[nv*128 u16]
  char* p = (char*)d_ws;
  int*    cnt   = (int*)p;            p += (size_t)nv * 4;
  float*  scale = (float*)p;          p += C_OUT * 4;
  float*  shift = (float*)p;          p += C_OUT * 4;
  float*  red   = (float*)p;          p += 256 * 4;
  float*  part  = (float*)p;          p += (size_t)256 * GB * 4;
  ushort* dwt   = (ushort*)p;         p += (size_t)C_OUT * CM * 2;
  ushort* swt   = (ushort*)p;         p += (size_t)CM * 32 * 2;
  int*    slots = (int*)p;            p += (size_t)nv * CAP * 4;
  ushort* g     = (ushort*)p;         p += (size_t)nf * C_OUT * 2;
  ushort* pre   = (ushort*)p;

  hipMemsetAsync(cnt, 0, (size_t)nv * 4, stream);

  const int n_inc = nf * 3;
  const int fill_blocks = (n_inc + 255) / 256;
  k_prepfill<<<96 + fill_blocks, 256, 0, stream>>>(dw, sw, dwt, swt,
                                                   face, vt_map, cnt, slots, n_inc);

  const int ntiles_f = (nf + FT - 1) / FT;   // 3125
  k_faceg<<<GRIDF, 256, 0, stream>>>(inputs, fc, swt, dwt, g, ntiles_f);

  const int ntiles_v = (nv + 15) / 16;       // 6250
  k_gather<<<GB, 256, 0, stream>>>(g, cnt, slots, nf_cnt, bias, pre, part, nv, ntiles_v);

  k_red<<<256, 256, 0, stream>>>(part, red);
  k_fin<<<1, 128, 0, stream>>>(red, gamma, beta, scale, shift, 1.0f / (float)nv);

  const int n8 = (nv * C_OUT) / 8;           // 1.6M
  k_bn<<<2048, 256, 0, stream>>>(pre, scale, shift, out, n8);
}